// Round 1
// baseline (272.380 us; speedup 1.0000x reference)
//
#include <hip/hip_runtime.h>

typedef __attribute__((ext_vector_type(8))) short short8v;
typedef __attribute__((ext_vector_type(4))) float f32x4;
typedef __attribute__((ext_vector_type(4))) int int4v;
typedef __attribute__((ext_vector_type(4))) unsigned short u16x4;

#define MFMA(a, b, c) __builtin_amdgcn_mfma_f32_16x16x32_bf16(a, b, c, 0, 0, 0)

__device__ __forceinline__ unsigned short f2bf(float f) {
  unsigned int u = __builtin_bit_cast(unsigned int, f);
  return (unsigned short)((u + 0x7FFFu + ((u >> 16) & 1u)) >> 16);
}
__device__ __forceinline__ float bf2f(unsigned short s) {
  return __builtin_bit_cast(float, (unsigned int)s << 16);
}

// ---------------- cast fp32 -> bf16, vectorized ----------------
__global__ __launch_bounds__(256) void cast_bf16(const float* __restrict__ src,
                                                 unsigned short* __restrict__ dst,
                                                 int n4) {
  int i = blockIdx.x * 256 + threadIdx.x;
  if (i >= n4) return;
  f32x4 v = *(const f32x4*)(src + (size_t)i * 4);
  u16x4 o;
#pragma unroll
  for (int j = 0; j < 4; ++j) o[j] = f2bf(v[j]);
  *(u16x4*)(dst + (size_t)i * 4) = o;
}

// ---------------- GEMM: out = A[M,1024] @ Bm[N,1024]^T ----------------
// MODE 0: QKV gemm. epilogue adds q/v bias, scatters to qn/kn [B,H,L,D] and vt [B,H,D,L] (bf16)
// MODE 1: proj gemm. epilogue adds b_proj, writes fp32 out [4096,1024]
template <int MODE>
__global__ __launch_bounds__(256) void gemm_bt(
    const unsigned short* __restrict__ A, const unsigned short* __restrict__ Bm,
    unsigned short* __restrict__ qn, unsigned short* __restrict__ kn,
    unsigned short* __restrict__ vt, float* __restrict__ outf,
    const float* __restrict__ bias_q, const float* __restrict__ bias_v) {
  __shared__ unsigned short Asl[128][72];
  __shared__ unsigned short Bsl[128][72];
  const int tid = threadIdx.x;
  const int lane = tid & 63;
  const int wave = tid >> 6;
  const int wr = wave >> 1, wc = wave & 1;
  const int c = lane & 15, g = lane >> 4;
  const int rowBase = blockIdx.x * 128;
  const int colBase = blockIdx.y * 128;

  f32x4 acc[4][4];
#pragma unroll
  for (int m = 0; m < 4; ++m)
#pragma unroll
    for (int n = 0; n < 4; ++n) acc[m][n] = (f32x4){0.f, 0.f, 0.f, 0.f};

  for (int k0 = 0; k0 < 1024; k0 += 64) {
#pragma unroll
    for (int it = 0; it < 4; ++it) {
      int idx = (tid + it * 256) * 8;
      int r = idx >> 6, cc = idx & 63;
      *(int4v*)&Asl[r][cc] = *(const int4v*)(A + (rowBase + r) * 1024 + k0 + cc);
      *(int4v*)&Bsl[r][cc] = *(const int4v*)(Bm + (colBase + r) * 1024 + k0 + cc);
    }
    __syncthreads();
#pragma unroll
    for (int kk = 0; kk < 2; ++kk) {
      short8v af[4], bf[4];
#pragma unroll
      for (int m = 0; m < 4; ++m)
        af[m] = *(const short8v*)&Asl[wr * 64 + m * 16 + c][kk * 32 + g * 8];
#pragma unroll
      for (int n = 0; n < 4; ++n)
        bf[n] = *(const short8v*)&Bsl[wc * 64 + n * 16 + c][kk * 32 + g * 8];
#pragma unroll
      for (int m = 0; m < 4; ++m)
#pragma unroll
        for (int n = 0; n < 4; ++n) acc[m][n] = MFMA(af[m], bf[n], acc[m][n]);
    }
    __syncthreads();
  }

#pragma unroll
  for (int m = 0; m < 4; ++m) {
#pragma unroll
    for (int n = 0; n < 4; ++n) {
#pragma unroll
      for (int r = 0; r < 4; ++r) {
        int grow = rowBase + wr * 64 + m * 16 + g * 4 + r;
        int gcol = colBase + wc * 64 + n * 16 + c;
        float v = acc[m][n][r];
        if constexpr (MODE == 1) {
          outf[grow * 1024 + gcol] = v + bias_q[gcol];
        } else {
          int s = gcol >> 10;
          int j = gcol & 1023;
          int hh = j >> 6, d = j & 63;
          int bb = grow >> 11, l = grow & 2047;
          float bias = (s == 0) ? bias_q[j] : ((s == 2) ? bias_v[j] : 0.0f);
          unsigned short o = f2bf(v + bias);
          int bhh = bb * 16 + hh;
          if (s == 0)
            qn[(bhh * 2048 + l) * 64 + d] = o;
          else if (s == 1)
            kn[(bhh * 2048 + l) * 64 + d] = o;
          else
            vt[(bhh * 64 + d) * 2048 + l] = o;
        }
      }
    }
  }
}

// ---------------- l2norm over D=64, one wave per row ----------------
__global__ __launch_bounds__(256) void norm_qk(unsigned short* __restrict__ qn,
                                               unsigned short* __restrict__ kn,
                                               const float* __restrict__ scale_mul) {
  int gw = (blockIdx.x * 256 + threadIdx.x) >> 6;  // 0 .. 131071
  int lane = threadIdx.x & 63;
  int isK = gw >> 16;
  int row = gw & 0xFFFF;  // (b*16+h)*2048 + l
  unsigned short* buf = isK ? kn : qn;
  float x = bf2f(buf[row * 64 + lane]);
  float s = x * x;
#pragma unroll
  for (int m = 1; m < 64; m <<= 1) s += __shfl_xor(s, m);
  float sc = 1.0f / fmaxf(sqrtf(s), 1e-12f);
  if (!isK) {
    int hh = (row >> 11) & 15;
    sc *= __expf(fminf(scale_mul[hh], 4.605170185988091f));  // ln(100)
  }
  buf[row * 64 + lane] = f2bf(x * sc);
}

// ---------------- flash attention: QB=64, KB=64, 4 waves ----------------
__global__ __launch_bounds__(256) void attn_fwd(
    const unsigned short* __restrict__ qn, const unsigned short* __restrict__ kn,
    const unsigned short* __restrict__ vt, const unsigned short* __restrict__ biasb,
    unsigned short* __restrict__ oup) {
  __shared__ unsigned short Ksl[64][72];
  __shared__ unsigned short Vsl[64][72];
  __shared__ unsigned short Psl[4][16][72];

  const int tid = threadIdx.x;
  const int lane = tid & 63;
  const int wave = tid >> 6;
  const int c = lane & 15, g = lane >> 4;
  const int qt = blockIdx.x;
  const int bh = blockIdx.y;
  const int b = bh >> 4, h = bh & 15;
  const int qbase = qt * 64;

  // Q fragments held in registers for the whole kernel (A-operand: row=lane&15)
  const unsigned short* qptr = qn + (bh * 2048 + qbase + wave * 16 + c) * 64;
  short8v qf0 = *(const short8v*)(qptr + g * 8);
  short8v qf1 = *(const short8v*)(qptr + 32 + g * 8);

  const unsigned short* kb = kn + bh * 2048 * 64;
  const unsigned short* vb = vt + bh * 64 * 2048;

  float m_run[4], l_run[4];
  f32x4 o_acc[4];
#pragma unroll
  for (int r = 0; r < 4; ++r) { m_run[r] = -1e30f; l_run[r] = 0.f; }
#pragma unroll
  for (int n = 0; n < 4; ++n) o_acc[n] = (f32x4){0.f, 0.f, 0.f, 0.f};

  for (int kt = 0; kt < 32; ++kt) {
#pragma unroll
    for (int it = 0; it < 2; ++it) {
      int idx = (tid + it * 256) * 8;
      int r = idx >> 6, cc = idx & 63;
      *(int4v*)&Ksl[r][cc] = *(const int4v*)(kb + (kt * 64 + r) * 64 + cc);
      *(int4v*)&Vsl[r][cc] = *(const int4v*)(vb + r * 2048 + kt * 64 + cc);
    }
    __syncthreads();

    // S = Q @ K^T + bias   (bias preloaded as the MFMA C operand)
    const int qrow0 = qbase + wave * 16 + g * 4;
    f32x4 s[4];
#pragma unroll
    for (int n = 0; n < 4; ++n) {
#pragma unroll
      for (int r = 0; r < 4; ++r)
        s[n][r] = bf2f(biasb[(qrow0 + r) * 2048 + kt * 64 + n * 16 + c]);
      short8v bk0 = *(const short8v*)&Ksl[n * 16 + c][g * 8];
      short8v bk1 = *(const short8v*)&Ksl[n * 16 + c][32 + g * 8];
      s[n] = MFMA(qf0, bk0, s[n]);
      s[n] = MFMA(qf1, bk1, s[n]);
    }

    // online softmax (each 16-lane group owns 4 q-rows)
#pragma unroll
    for (int r = 0; r < 4; ++r) {
      float mx = fmaxf(fmaxf(s[0][r], s[1][r]), fmaxf(s[2][r], s[3][r]));
      mx = fmaxf(mx, __shfl_xor(mx, 1));
      mx = fmaxf(mx, __shfl_xor(mx, 2));
      mx = fmaxf(mx, __shfl_xor(mx, 4));
      mx = fmaxf(mx, __shfl_xor(mx, 8));
      float mnew = fmaxf(m_run[r], mx);
      float so = __expf(m_run[r] - mnew);
      m_run[r] = mnew;
      float rs = 0.f;
#pragma unroll
      for (int n = 0; n < 4; ++n) {
        float e = __expf(s[n][r] - mnew);
        Psl[wave][g * 4 + r][n * 16 + c] = f2bf(e);
        rs += e;
      }
      rs += __shfl_xor(rs, 1);
      rs += __shfl_xor(rs, 2);
      rs += __shfl_xor(rs, 4);
      rs += __shfl_xor(rs, 8);
      l_run[r] = l_run[r] * so + rs;
#pragma unroll
      for (int n = 0; n < 4; ++n) o_acc[n][r] *= so;
    }

    asm volatile("s_waitcnt lgkmcnt(0)" ::: "memory");

    // O += P @ V  (P from per-wave LDS; V^T layout gives contiguous b128 reads)
#pragma unroll
    for (int kk = 0; kk < 2; ++kk) {
      short8v pf = *(const short8v*)&Psl[wave][c][kk * 32 + g * 8];
#pragma unroll
      for (int n = 0; n < 4; ++n) {
        short8v vf = *(const short8v*)&Vsl[n * 16 + c][kk * 32 + g * 8];
        o_acc[n] = MFMA(pf, vf, o_acc[n]);
      }
    }
    __syncthreads();
  }

  const int orow = b * 2048 + qbase + wave * 16 + g * 4;
#pragma unroll
  for (int n = 0; n < 4; ++n)
#pragma unroll
    for (int r = 0; r < 4; ++r)
      oup[(orow + r) * 1024 + h * 64 + n * 16 + c] = f2bf(o_acc[n][r] / l_run[r]);
}

// ---------------- host launch ----------------
extern "C" void kernel_launch(void* const* d_in, const int* in_sizes, int n_in,
                              void* d_out, int out_size, void* d_ws, size_t ws_size,
                              hipStream_t stream) {
  const float* x = (const float*)d_in[0];
  const float* attn_bias = (const float*)d_in[1];
  const float* w_qkv = (const float*)d_in[2];
  const float* q_bias = (const float*)d_in[3];
  const float* v_bias = (const float*)d_in[4];
  const float* scale_mul = (const float*)d_in[5];
  const float* w_proj = (const float*)d_in[6];
  const float* b_proj = (const float*)d_in[7];
  float* out = (float*)d_out;

  char* ws = (char*)d_ws;
  // lifetimes: xb dies after gemm1; oup born at attn -> alias. total 48 MB.
  unsigned short* xb = (unsigned short*)(ws);                   // [4096][1024] bf16 (8MB)
  unsigned short* oup = (unsigned short*)(ws);                  // [4096][1024] bf16 (alias)
  unsigned short* wqkvb = (unsigned short*)(ws + (8 << 20));    // [3072][1024] (6MB)
  unsigned short* wprojb = (unsigned short*)(ws + (14 << 20));  // [1024][1024] (2MB)
  unsigned short* biasb = (unsigned short*)(ws + (16 << 20));   // [2048][2048] (8MB)
  unsigned short* qn = (unsigned short*)(ws + (24 << 20));      // [32][2048][64] (8MB)
  unsigned short* kn = (unsigned short*)(ws + (32 << 20));      // [32][2048][64] (8MB)
  unsigned short* vt = (unsigned short*)(ws + (40 << 20));      // [32][64][2048] (8MB)

  cast_bf16<<<4096, 256, 0, stream>>>(x, xb, 4096 * 1024 / 4);
  cast_bf16<<<3072, 256, 0, stream>>>(w_qkv, wqkvb, 3072 * 1024 / 4);
  cast_bf16<<<1024, 256, 0, stream>>>(w_proj, wprojb, 1024 * 1024 / 4);
  cast_bf16<<<4096, 256, 0, stream>>>(attn_bias, biasb, 2048 * 2048 / 4);

  gemm_bt<0><<<dim3(32, 24), 256, 0, stream>>>(xb, wqkvb, qn, kn, vt, nullptr,
                                               q_bias, v_bias);
  norm_qk<<<32768, 256, 0, stream>>>(qn, kn, scale_mul);
  attn_fwd<<<dim3(32, 32), 256, 0, stream>>>(qn, kn, vt, biasb, oup);
  gemm_bt<1><<<dim3(32, 8), 256, 0, stream>>>(oup, wprojb, nullptr, nullptr,
                                              nullptr, out, b_proj, nullptr);
}

// Round 2
// 211.169 us; speedup vs baseline: 1.2899x; 1.2899x over previous
//
#include <hip/hip_runtime.h>

typedef __attribute__((ext_vector_type(8))) short short8v;
typedef __attribute__((ext_vector_type(4))) float f32x4;
typedef __attribute__((ext_vector_type(16))) float f32x16;
typedef __attribute__((ext_vector_type(4))) int int4v;
typedef __attribute__((ext_vector_type(4))) unsigned int uint4v;
typedef __attribute__((ext_vector_type(4))) unsigned short u16x4;

#define MFMA16(a, b, c) __builtin_amdgcn_mfma_f32_16x16x32_bf16(a, b, c, 0, 0, 0)
#define MFMA32(a, b, c) __builtin_amdgcn_mfma_f32_32x32x16_bf16(a, b, c, 0, 0, 0)

__device__ __forceinline__ unsigned short f2bf(float f) {
  unsigned int u = __builtin_bit_cast(unsigned int, f);
  return (unsigned short)((u + 0x7FFFu + ((u >> 16) & 1u)) >> 16);
}
__device__ __forceinline__ float bf2f(unsigned short s) {
  return __builtin_bit_cast(float, (unsigned int)s << 16);
}
// exact HW op: 2^x
__device__ __forceinline__ float exp2_hw(float x) {
  float r;
  asm("v_exp_f32 %0, %1" : "=v"(r) : "v"(x));
  return r;
}

// ---------------- cast fp32 -> bf16 (optionally scaled), vectorized ----------------
__global__ __launch_bounds__(256) void cast_bf16(const float* __restrict__ src,
                                                 unsigned short* __restrict__ dst,
                                                 int n4, float scale) {
  int i = blockIdx.x * 256 + threadIdx.x;
  if (i >= n4) return;
  f32x4 v = *(const f32x4*)(src + (size_t)i * 4);
  u16x4 o;
#pragma unroll
  for (int j = 0; j < 4; ++j) o[j] = f2bf(v[j] * scale);
  *(u16x4*)(dst + (size_t)i * 4) = o;
}

// ---------------- GEMM: out = A[M,1024] @ Bm[N,1024]^T ----------------
// MODE 0: QKV gemm -> scatter q,k [B,H,L,D], v transposed [B,H,D,L]
// MODE 1: proj gemm -> fp32 out
template <int MODE>
__global__ __launch_bounds__(256) void gemm_bt(
    const unsigned short* __restrict__ A, const unsigned short* __restrict__ Bm,
    unsigned short* __restrict__ qn, unsigned short* __restrict__ kn,
    unsigned short* __restrict__ vt, float* __restrict__ outf,
    const float* __restrict__ bias_q, const float* __restrict__ bias_v) {
  __shared__ unsigned short Asl[128][72];
  __shared__ unsigned short Bsl[128][72];
  const int tid = threadIdx.x;
  const int lane = tid & 63;
  const int wave = tid >> 6;
  const int wr = wave >> 1, wc = wave & 1;
  const int c = lane & 15, g = lane >> 4;
  const int rowBase = blockIdx.x * 128;
  const int colBase = blockIdx.y * 128;

  f32x4 acc[4][4];
#pragma unroll
  for (int m = 0; m < 4; ++m)
#pragma unroll
    for (int n = 0; n < 4; ++n) acc[m][n] = (f32x4){0.f, 0.f, 0.f, 0.f};

  for (int k0 = 0; k0 < 1024; k0 += 64) {
#pragma unroll
    for (int it = 0; it < 4; ++it) {
      int idx = (tid + it * 256) * 8;
      int r = idx >> 6, cc = idx & 63;
      *(int4v*)&Asl[r][cc] = *(const int4v*)(A + (rowBase + r) * 1024 + k0 + cc);
      *(int4v*)&Bsl[r][cc] = *(const int4v*)(Bm + (colBase + r) * 1024 + k0 + cc);
    }
    __syncthreads();
#pragma unroll
    for (int kk = 0; kk < 2; ++kk) {
      short8v af[4], bf[4];
#pragma unroll
      for (int m = 0; m < 4; ++m)
        af[m] = *(const short8v*)&Asl[wr * 64 + m * 16 + c][kk * 32 + g * 8];
#pragma unroll
      for (int n = 0; n < 4; ++n)
        bf[n] = *(const short8v*)&Bsl[wc * 64 + n * 16 + c][kk * 32 + g * 8];
#pragma unroll
      for (int m = 0; m < 4; ++m)
#pragma unroll
        for (int n = 0; n < 4; ++n) acc[m][n] = MFMA16(af[m], bf[n], acc[m][n]);
    }
    __syncthreads();
  }

#pragma unroll
  for (int m = 0; m < 4; ++m) {
#pragma unroll
    for (int n = 0; n < 4; ++n) {
#pragma unroll
      for (int r = 0; r < 4; ++r) {
        int grow = rowBase + wr * 64 + m * 16 + g * 4 + r;
        int gcol = colBase + wc * 64 + n * 16 + c;
        float v = acc[m][n][r];
        if constexpr (MODE == 1) {
          outf[grow * 1024 + gcol] = v + bias_q[gcol];
        } else {
          int s = gcol >> 10;
          int j = gcol & 1023;
          int hh = j >> 6, d = j & 63;
          int bb = grow >> 11, l = grow & 2047;
          float bias = (s == 0) ? bias_q[j] : ((s == 2) ? bias_v[j] : 0.0f);
          unsigned short o = f2bf(v + bias);
          int bhh = bb * 16 + hh;
          if (s == 0)
            qn[(bhh * 2048 + l) * 64 + d] = o;
          else if (s == 1)
            kn[(bhh * 2048 + l) * 64 + d] = o;
          else
            vt[(bhh * 64 + d) * 2048 + l] = o;
        }
      }
    }
  }
}

// ---------------- l2norm over D=64, one wave per row; q gets sm*log2e folded in ----------------
__global__ __launch_bounds__(256) void norm_qk(unsigned short* __restrict__ qn,
                                               unsigned short* __restrict__ kn,
                                               const float* __restrict__ scale_mul) {
  int gw = (blockIdx.x * 256 + threadIdx.x) >> 6;  // 0 .. 131071
  int lane = threadIdx.x & 63;
  int isK = gw >> 16;
  int row = gw & 0xFFFF;  // (b*16+h)*2048 + l
  unsigned short* buf = isK ? kn : qn;
  float x = bf2f(buf[row * 64 + lane]);
  float s = x * x;
#pragma unroll
  for (int m = 1; m < 64; m <<= 1) s += __shfl_xor(s, m);
  float sc = 1.0f / fmaxf(sqrtf(s), 1e-12f);
  if (!isK) {
    int hh = (row >> 11) & 15;
    // fold softmax base-2 conversion into q: * log2(e)
    sc *= __expf(fminf(scale_mul[hh], 4.605170185988091f)) * 1.44269504088896f;
  }
  buf[row * 64 + lane] = f2bf(x * sc);
}

// ---------------- flash attention, swapped QK^T (32x32 MFMA), in-register softmax ----
// 4 waves x 32 q-rows = 128 q/block; KV tile 64. S^T = mfma(K, Q): lane owns q = lane&31.
__global__ __launch_bounds__(256) void attn_fwd(
    const unsigned short* __restrict__ qn, const unsigned short* __restrict__ kn,
    const unsigned short* __restrict__ vt, const unsigned short* __restrict__ biasb,
    unsigned short* __restrict__ oup) {
  __shared__ unsigned short Ksl[64][72];
  __shared__ unsigned short Vsl[64][72];
  const int tid = threadIdx.x;
  const int lane = tid & 63;
  const int wave = tid >> 6;
  const int c5 = lane & 31;
  const int h = lane >> 5;
  const int qt = blockIdx.x;   // 16
  const int bh = blockIdx.y;   // 32
  const int b = bh >> 4, hd = bh & 15;
  const int q = qt * 128 + wave * 32 + c5;  // this lane's softmax row

  // Q as B-operand fragments, resident whole kernel: Q[q=c5][d = kd*16 + 8h + j]
  short8v qf[4];
  {
    const unsigned short* qp = qn + ((size_t)bh * 2048 + q) * 64 + h * 8;
#pragma unroll
    for (int kd = 0; kd < 4; ++kd) qf[kd] = *(const short8v*)(qp + kd * 16);
  }
  const unsigned short* kb = kn + (size_t)bh * 2048 * 64;
  const unsigned short* vb = vt + (size_t)bh * 64 * 2048;
  const unsigned short* bq = biasb + (size_t)q * 2048 + h * 4;

  float m_run = -1e30f, l_run = 0.0f;
  f32x16 o0 = {}, o1 = {};

  for (int kt = 0; kt < 32; ++kt) {
    if (kt) __syncthreads();
    // stage K tile [64 k][64 d] and V tile [64 d][64 l], padded stride 72
#pragma unroll
    for (int i = 0; i < 2; ++i) {
      int flat = tid * 8 + i * 2048;
      int r = flat >> 6, cc = flat & 63;
      *(int4v*)&Ksl[r][cc] = *(const int4v*)(kb + (kt * 64 + r) * 64 + cc);
      *(int4v*)&Vsl[r][cc] = *(const int4v*)(vb + r * 2048 + kt * 64 + cc);
    }
    __syncthreads();

    // bias loads first (latency hidden under MFMAs); k contiguous per lane now
    u16x4 b4[2][4];
#pragma unroll
    for (int n = 0; n < 2; ++n)
#pragma unroll
      for (int Qd = 0; Qd < 4; ++Qd)
        b4[n][Qd] = *(const u16x4*)(bq + kt * 64 + n * 32 + Qd * 8);

    // S^T[k][q]: two 32x32 tiles over k
    f32x16 s[2];
#pragma unroll
    for (int n = 0; n < 2; ++n)
#pragma unroll
      for (int e = 0; e < 16; ++e) s[n][e] = 0.0f;
#pragma unroll
    for (int n = 0; n < 2; ++n)
#pragma unroll
      for (int kd = 0; kd < 4; ++kd) {
        short8v kf = *(const short8v*)&Ksl[n * 32 + c5][kd * 16 + h * 8];
        s[n] = MFMA32(kf, qf[kd], s[n]);
      }
    // += bias (already *log2e): k row of reg e is (e&3)+8*(e>>2)+4h
#pragma unroll
    for (int n = 0; n < 2; ++n)
#pragma unroll
      for (int Qd = 0; Qd < 4; ++Qd)
#pragma unroll
        for (int r = 0; r < 4; ++r) s[n][Qd * 4 + r] += bf2f(b4[n][Qd][r]);

    // online softmax over this lane's q-row (32 in-lane + partner half)
    float pmax = s[0][0];
#pragma unroll
    for (int e = 1; e < 16; ++e) pmax = fmaxf(pmax, s[0][e]);
#pragma unroll
    for (int e = 0; e < 16; ++e) pmax = fmaxf(pmax, s[1][e]);
    pmax = fmaxf(pmax, __shfl_xor(pmax, 32));

    if (!__all(pmax - m_run <= 8.0f)) {  // defer-max (T13)
      float mnew = fmaxf(m_run, pmax);
      float so = exp2_hw(m_run - mnew);
      m_run = mnew;
      l_run *= so;
#pragma unroll
      for (int e = 0; e < 16; ++e) {
        int ql = (e & 3) + 8 * (e >> 2) + 4 * h;
        float sreg = __shfl(so, ql);
        o0[e] *= sreg;
        o1[e] *= sreg;
      }
    }

    float rs = 0.0f;
#pragma unroll
    for (int n = 0; n < 2; ++n)
#pragma unroll
      for (int e = 0; e < 16; ++e) {
        float p = exp2_hw(s[n][e] - m_run);
        s[n][e] = p;
        rs += p;
      }
    rs += __shfl_xor(rs, 32);
    l_run += rs;

    // pack P to bf16 pairs: w[n][Qd][u] covers k = n*32 + 8*Qd + 4h + 2u + {0,1}
    unsigned int w[2][4][2];
#pragma unroll
    for (int n = 0; n < 2; ++n)
#pragma unroll
      for (int Qd = 0; Qd < 4; ++Qd) {
        asm("v_cvt_pk_bf16_f32 %0, %1, %2"
            : "=v"(w[n][Qd][0]) : "v"(s[n][Qd * 4 + 0]), "v"(s[n][Qd * 4 + 1]));
        asm("v_cvt_pk_bf16_f32 %0, %1, %2"
            : "=v"(w[n][Qd][1]) : "v"(s[n][Qd * 4 + 2]), "v"(s[n][Qd * 4 + 3]));
      }

    // build A-frags (P[q=c5][k]) via half-wave exchange, then PV
#pragma unroll
    for (int n = 0; n < 2; ++n)
#pragma unroll
      for (int kc = 0; kc < 2; ++kc) {
        unsigned int W[4];
#pragma unroll
        for (int u = 0; u < 2; ++u) {
          unsigned int A = w[n][kc * 2][u];
          unsigned int B = w[n][kc * 2 + 1][u];
          unsigned int pub = h ? A : B;            // publish what partner half needs
          unsigned int ex = (unsigned int)__shfl_xor((int)pub, 32);
          W[u] = h ? ex : A;
          W[2 + u] = h ? B : ex;
        }
        uint4v wv = {W[0], W[1], W[2], W[3]};
        short8v pa = __builtin_bit_cast(short8v, wv);
        short8v v0 = *(const short8v*)&Vsl[c5][n * 32 + kc * 16 + h * 8];
        short8v v1 = *(const short8v*)&Vsl[32 + c5][n * 32 + kc * 16 + h * 8];
        o0 = MFMA32(pa, v0, o0);
        o1 = MFMA32(pa, v1, o1);
      }
  }

  // epilogue: O / l, write bf16 rows (coalesced across c5)
#pragma unroll
  for (int e = 0; e < 16; ++e) {
    int ql = (e & 3) + 8 * (e >> 2) + 4 * h;
    float lq = __shfl(l_run, ql);
    float inv = 1.0f / lq;
    int grow = b * 2048 + qt * 128 + wave * 32 + ql;
    oup[(size_t)grow * 1024 + hd * 64 + c5] = f2bf(o0[e] * inv);
    oup[(size_t)grow * 1024 + hd * 64 + 32 + c5] = f2bf(o1[e] * inv);
  }
}

// ---------------- host launch ----------------
extern "C" void kernel_launch(void* const* d_in, const int* in_sizes, int n_in,
                              void* d_out, int out_size, void* d_ws, size_t ws_size,
                              hipStream_t stream) {
  const float* x = (const float*)d_in[0];
  const float* attn_bias = (const float*)d_in[1];
  const float* w_qkv = (const float*)d_in[2];
  const float* q_bias = (const float*)d_in[3];
  const float* v_bias = (const float*)d_in[4];
  const float* scale_mul = (const float*)d_in[5];
  const float* w_proj = (const float*)d_in[6];
  const float* b_proj = (const float*)d_in[7];
  float* out = (float*)d_out;

  char* ws = (char*)d_ws;
  unsigned short* xb = (unsigned short*)(ws);                   // [4096][1024] bf16 (8MB)
  unsigned short* oup = (unsigned short*)(ws);                  // alias (disjoint lifetime)
  unsigned short* wqkvb = (unsigned short*)(ws + (8 << 20));    // [3072][1024]
  unsigned short* wprojb = (unsigned short*)(ws + (14 << 20));  // [1024][1024]
  unsigned short* biasb = (unsigned short*)(ws + (16 << 20));   // [2048][2048] (*log2e)
  unsigned short* qn = (unsigned short*)(ws + (24 << 20));      // [32][2048][64]
  unsigned short* kn = (unsigned short*)(ws + (32 << 20));      // [32][2048][64]
  unsigned short* vt = (unsigned short*)(ws + (40 << 20));      // [32][64][2048]

  const float LOG2E = 1.44269504088896f;
  cast_bf16<<<4096, 256, 0, stream>>>(x, xb, 4096 * 1024 / 4, 1.0f);
  cast_bf16<<<3072, 256, 0, stream>>>(w_qkv, wqkvb, 3072 * 1024 / 4, 1.0f);
  cast_bf16<<<1024, 256, 0, stream>>>(w_proj, wprojb, 1024 * 1024 / 4, 1.0f);
  cast_bf16<<<4096, 256, 0, stream>>>(attn_bias, biasb, 2048 * 2048 / 4, LOG2E);

  gemm_bt<0><<<dim3(32, 24), 256, 0, stream>>>(xb, wqkvb, qn, kn, vt, nullptr,
                                               q_bias, v_bias);
  norm_qk<<<32768, 256, 0, stream>>>(qn, kn, scale_mul);
  attn_fwd<<<dim3(16, 32), 256, 0, stream>>>(qn, kn, vt, biasb, oup);
  gemm_bt<1><<<dim3(32, 8), 256, 0, stream>>>(oup, wprojb, nullptr, nullptr,
                                              nullptr, out, b_proj, nullptr);
}